// Round 12
// baseline (400.367 us; speedup 1.0000x reference)
//
#include <hip/hip_runtime.h>
#include <hip/hip_cooperative_groups.h>

namespace cg = cooperative_groups;

typedef unsigned short u16;
typedef unsigned int u32;
typedef __bf16 bf16x8 __attribute__((ext_vector_type(8)));
typedef float f32x4 __attribute__((ext_vector_type(4)));

#define N_NODES 10000
#define N_EDGES 160000
#define D_IN 512
#define D_HID 1024

#define AS1 __attribute__((address_space(1)))
#define AS3 __attribute__((address_space(3)))

__device__ __forceinline__ u16 f2bf(float f) {
    union { float f; u32 u; } v; v.f = f;
    return (u16)((v.u + 0x7fffu + ((v.u >> 16) & 1u)) >> 16);
}
__device__ __forceinline__ float b2f(u32 h) {
    union { u32 u; float f; } v; v.u = h << 16; return v.f;
}

// ---- cooperative CSR build: zero -> hist -> scan -> reorder in ONE dispatch
// (replaces memset + hist_k + scan_k + reorder_k = 4 graph nodes; the ~5us
// per-boundary overhead was the largest untargeted cost left). 625 blocks x
// 256 thr, tiny VGPR/LDS -> co-residency (<=8 blk/CU x 256 CU >> 625) is
// guaranteed, which hipLaunchCooperativeKernel additionally enforces. ----
__global__ __launch_bounds__(256) void csr_k(const int* __restrict__ src,
                                             const int* __restrict__ dst,
                                             int* __restrict__ counts,
                                             int* __restrict__ offs,
                                             int* __restrict__ cursor,
                                             int* __restrict__ ssrc) {
    cg::grid_group grid = cg::this_grid();
    const int b = blockIdx.x, t = threadIdx.x;
    const int gid = b * 256 + t;          // 625*256 = 160000 = N_EDGES

    // P0: zero counts
    if (gid < N_NODES) counts[gid] = 0;
    grid.sync();
    // P1: histogram of dst
    if (gid < N_EDGES) atomicAdd(&counts[dst[gid]], 1);
    grid.sync();
    // P2: exclusive scan (block 0 only; 256 thr x 40 elems = 10240 >= 10000)
    if (b == 0) {
        __shared__ int wpre[4];
        __shared__ int wsum[4];
        const int l = t & 63, w = t >> 6;
        const int base = t * 40;
        int lsum = 0;
        for (int i = 0; i < 40; i++) {
            int idx = base + i;
            lsum += (idx < N_NODES) ? counts[idx] : 0;
        }
        int sc = lsum;
#pragma unroll
        for (int d = 1; d < 64; d <<= 1) {
            int v = __shfl_up(sc, d);
            if (l >= d) sc += v;
        }
        if (l == 63) wsum[w] = sc;
        __syncthreads();
        if (w == 0 && l < 4) {
            int v = wsum[l];
            int p = v;
#pragma unroll
            for (int d = 1; d < 4; d <<= 1) {
                int u = __shfl_up(p, d);
                if (l >= d) p += u;
            }
            wpre[l] = p - v;
        }
        __syncthreads();
        int run = wpre[w] + sc - lsum;    // exclusive prefix for this chunk
        for (int i = 0; i < 40; i++) {
            int idx = base + i;
            if (idx < N_NODES) {
                int c = counts[idx];
                offs[idx] = run; cursor[idx] = run; run += c;
            }
        }
        if (t == 255) offs[N_NODES] = run;   // t255's chunk is all >=N -> run = total
    }
    grid.sync();
    // P3: reorder edges into dst-sorted order
    if (gid < N_EDGES) {
        int d = dst[gid];
        int pos = atomicAdd(&cursor[d], 1);
        ssrc[pos] = src[gid];
    }
}

// ---- fused prep: cvt feat->bf16 (2500 blk) | transW (1024 blk) ----
// (replaces cvt_bf16_k + transw_k = 2 graph nodes; block-partition proven r5)
__global__ __launch_bounds__(256) void prep_k(const float* __restrict__ feat,
                                              u16* __restrict__ featb,
                                              const float* __restrict__ W1,
                                              u16* __restrict__ w1t,
                                              const float* __restrict__ W2,
                                              u16* __restrict__ w2t) {
    int b = blockIdx.x;
    int t = threadIdx.x;
    if (b < 2500) {                       // cvt feat -> bf16, 8/thread
        int i = (b * 256 + t) * 8;
        float4 a = *(const float4*)(feat + i);
        float4 c = *(const float4*)(feat + i + 4);
        uint4 o;
        o.x = (u32)f2bf(a.x) | ((u32)f2bf(a.y) << 16);
        o.y = (u32)f2bf(a.z) | ((u32)f2bf(a.w) << 16);
        o.z = (u32)f2bf(c.x) | ((u32)f2bf(c.y) << 16);
        o.w = (u32)f2bf(c.z) | ((u32)f2bf(c.w) << 16);
        *(uint4*)(featb + i) = o;
        return;
    }
    // transpose+convert: WT[n][k] = bf16(W[k][n])
    __shared__ float tile[32][33];
    b -= 2500;
    const float* W; u16* WT; int K, N, nt;
    if (b < 512) { W = W1; WT = w1t; K = D_IN;  N = D_HID; nt = 32; }
    else         { b -= 512; W = W2; WT = w2t; K = D_HID; N = D_IN;  nt = 16; }
    int n0 = (b % nt) * 32, k0 = (b / nt) * 32;
    int tx = t & 31, ty = t >> 5;
#pragma unroll
    for (int i = 0; i < 32; i += 8)
        tile[ty + i][tx] = W[(size_t)(k0 + ty + i) * N + n0 + tx];
    __syncthreads();
#pragma unroll
    for (int i = 0; i < 32; i += 8)
        WT[(size_t)(n0 + ty + i) * K + k0 + tx] = f2bf(tile[tx][ty + i]);
}

// ---- gather-sum from bf16 feat + (1+eps)*fp32 self, write bf16 ----
// one wave (64 lanes) per node, 8 bf16 per lane; 8 edges in flight per iter
__global__ __launch_bounds__(128) void gather_k(const float* __restrict__ feat,
                                                const u16* __restrict__ featb,
                                                const float* __restrict__ eps,
                                                const int* __restrict__ offs,
                                                const int* __restrict__ ssrc,
                                                u16* __restrict__ out) {
    int n = (blockIdx.x * 128 + threadIdx.x) >> 6;
    int l = threadIdx.x & 63;
    if (n >= N_NODES) return;
    int beg = offs[n], end = offs[n + 1];
    float s = 1.0f + eps[0];
    float4 s0 = *(const float4*)(feat + (size_t)n * D_IN + l * 8);
    float4 s1 = *(const float4*)(feat + (size_t)n * D_IN + l * 8 + 4);
    float acc[8] = { s * s0.x, s * s0.y, s * s0.z, s * s0.w,
                     s * s1.x, s * s1.y, s * s1.z, s * s1.w };
#define ACC4(v) \
        acc[0] += b2f(v.x & 0xffffu); acc[1] += b2f(v.x >> 16); \
        acc[2] += b2f(v.y & 0xffffu); acc[3] += b2f(v.y >> 16); \
        acc[4] += b2f(v.z & 0xffffu); acc[5] += b2f(v.z >> 16); \
        acc[6] += b2f(v.w & 0xffffu); acc[7] += b2f(v.w >> 16);
    int e = beg;
    for (; e + 8 <= end; e += 8) {
        uint4 v[8];
#pragma unroll
        for (int q = 0; q < 8; q++) {
            int iq = ssrc[e + q];
            v[q] = *(const uint4*)(featb + (size_t)iq * D_IN + l * 8);
        }
#pragma unroll
        for (int q = 0; q < 8; q++) { ACC4(v[q]) }
    }
    for (; e + 4 <= end; e += 4) {
        int i0 = ssrc[e], i1 = ssrc[e + 1], i2 = ssrc[e + 2], i3 = ssrc[e + 3];
        uint4 v0 = *(const uint4*)(featb + (size_t)i0 * D_IN + l * 8);
        uint4 v1 = *(const uint4*)(featb + (size_t)i1 * D_IN + l * 8);
        uint4 v2 = *(const uint4*)(featb + (size_t)i2 * D_IN + l * 8);
        uint4 v3 = *(const uint4*)(featb + (size_t)i3 * D_IN + l * 8);
        ACC4(v0) ACC4(v1) ACC4(v2) ACC4(v3)
    }
    for (; e < end; e++) {
        int i0 = ssrc[e];
        uint4 v0 = *(const uint4*)(featb + (size_t)i0 * D_IN + l * 8);
        ACC4(v0)
    }
#undef ACC4
    uint4 o;
    o.x = (u32)f2bf(acc[0]) | ((u32)f2bf(acc[1]) << 16);
    o.y = (u32)f2bf(acc[2]) | ((u32)f2bf(acc[3]) << 16);
    o.z = (u32)f2bf(acc[4]) | ((u32)f2bf(acc[5]) << 16);
    o.w = (u32)f2bf(acc[6]) | ((u32)f2bf(acc[7]) << 16);
    *(uint4*)(out + (size_t)n * D_IN + l * 8) = o;
}

// ---- GEMM: C[M,N] = A[M,K] @ B[K,N]; A bf16 row-major, BT bf16 [N,K] ----
// r11 verbatim (best measured): 64x64 tile, one wave/block, BK=32, 3-buffer
// depth-2 pipeline with exact counted vmcnt (safe: single wave, no other
// VMEM in loop), pre-swizzled gload_lds staging, XCD-chunked remap.
// EPI=0: C = bf16(relu(acc + bias));  EPI=1: C = acc + bias + feat (fp32)
template <int EPI, int K>
__global__ __launch_bounds__(64) void gemm_k(const u16* __restrict__ A,
                                             const u16* __restrict__ BT,
                                             const float* __restrict__ bias,
                                             const float* __restrict__ feat,
                                             void* __restrict__ Cout,
                                             int M, int N) {
    __shared__ __bf16 sA[3][64 * 32];
    __shared__ __bf16 sB[3][64 * 32];

    const int NX = gridDim.x;
    const int nwg = NX * gridDim.y;
    const int flat = blockIdx.y * NX + blockIdx.x;
    const int qq = nwg >> 3, rr8 = nwg & 7;
    const int xcd = flat & 7, idx = flat >> 3;
    const int L = (xcd < rr8 ? xcd * (qq + 1) : rr8 * (qq + 1) + (xcd - rr8) * qq) + idx;
    int row0 = (L / NX) * 64;
    if (row0 > M - 64) row0 = M - 64;   // overlap last tile; dup rows benign
    const int col0 = (L % NX) * 64;

    const int l = threadIdx.x;
    const int lr = l & 15;
    const int lq = l >> 4;

    const int g8 = (((l & 3) ^ ((l >> 2) & 3)) * 8);
    const u16* bA = A  + (size_t)(row0 + (l >> 2)) * K + g8;
    const u16* bB = BT + (size_t)(col0 + (l >> 2)) * K + g8;
    const int fo = ((lq ^ (lr & 3)) * 8);

    f32x4 acc[4][4] = {};
    const int NT = K >> 5;   // k-tiles of 32

#define STAGE(buf, kt)                                                         \
    {                                                                          \
        const int ko_ = (kt) << 5;                                             \
        _Pragma("unroll")                                                      \
        for (int q_ = 0; q_ < 4; q_++) {                                       \
            __builtin_amdgcn_global_load_lds(                                  \
                (const AS1 void*)(bA + (size_t)q_ * 16 * K + ko_),             \
                (AS3 void*)(&sA[buf][q_ * 512]), 16, 0, 0);                    \
            __builtin_amdgcn_global_load_lds(                                  \
                (const AS1 void*)(bB + (size_t)q_ * 16 * K + ko_),             \
                (AS3 void*)(&sB[buf][q_ * 512]), 16, 0, 0);                    \
        }                                                                      \
    }

    STAGE(0, 0);
    STAGE(1, 1);

#pragma unroll
    for (int it = 0; it < NT; ++it) {
        const int cur = it % 3;
        if (it == NT - 1) {
            asm volatile("s_waitcnt vmcnt(0)" ::: "memory");
        } else {
            asm volatile("s_waitcnt vmcnt(8)" ::: "memory");
        }
        __builtin_amdgcn_sched_barrier(0);
        bf16x8 fa[4], fb[4];
#pragma unroll
        for (int i = 0; i < 4; i++)
            fa[i] = *(const bf16x8*)(&sA[cur][0] + (i * 16 + lr) * 32 + fo);
#pragma unroll
        for (int j = 0; j < 4; j++)
            fb[j] = *(const bf16x8*)(&sB[cur][0] + (j * 16 + lr) * 32 + fo);
        __builtin_amdgcn_sched_barrier(0);
        if (it + 2 < NT) STAGE((it + 2) % 3, it + 2);
        __builtin_amdgcn_sched_barrier(0);
#pragma unroll
        for (int i = 0; i < 4; i++)
#pragma unroll
            for (int j = 0; j < 4; j++)
                acc[i][j] = __builtin_amdgcn_mfma_f32_16x16x32_bf16(
                    fa[i], fb[j], acc[i][j], 0, 0, 0);
    }
#undef STAGE

#pragma unroll
    for (int i = 0; i < 4; i++) {
        int rowb = row0 + i * 16 + lq * 4;
#pragma unroll
        for (int j = 0; j < 4; j++) {
            int col = col0 + j * 16 + lr;
            float bv = bias[col];
#pragma unroll
            for (int r = 0; r < 4; r++) {
                int rr = rowb + r;
                float v = acc[i][j][r] + bv;
                if (EPI == 0) {
                    v = fmaxf(v, 0.0f);
                    ((u16*)Cout)[(size_t)rr * N + col] = f2bf(v);
                } else {
                    v += feat[(size_t)rr * N + col];
                    ((float*)Cout)[(size_t)rr * N + col] = v;
                }
            }
        }
    }
}

extern "C" void kernel_launch(void* const* d_in, const int* in_sizes, int n_in,
                              void* d_out, int out_size, void* d_ws, size_t ws_size,
                              hipStream_t stream) {
    const float* feat = (const float*)d_in[0];
    const float* W1   = (const float*)d_in[1];
    const float* b1   = (const float*)d_in[2];
    const float* W2   = (const float*)d_in[3];
    const float* b2   = (const float*)d_in[4];
    const float* eps  = (const float*)d_in[5];
    const int*   src  = (const int*)d_in[6];
    const int*   dst  = (const int*)d_in[7];
    float* out = (float*)d_out;

    char* ws = (char*)d_ws;
    u16* rst_b16 = (u16*)(ws);                        // 10,240,000 B
    u16* h_b16   = (u16*)(ws + 10240000);             // 20,480,000 B
    u16* featb   = (u16*)(ws + 30720000);             // 10,240,000 B
    u16* w1t     = (u16*)(ws + 40960000);             //  1,048,576 B
    u16* w2t     = (u16*)(ws + 42008576);             //  1,048,576 B
    int* counts  = (int*)(ws + 43057152);             //     40,000 B
    int* offs    = (int*)(ws + 43097152);             //     40,004 B
    int* cursor  = (int*)(ws + 43137160);             //     40,000 B
    int* ssrc    = (int*)(ws + 43177160);             //    640,000 B

    // 1) cooperative CSR build (zero + hist + scan + reorder in one node)
    {
        void* args[] = { (void*)&src, (void*)&dst, (void*)&counts,
                         (void*)&offs, (void*)&cursor, (void*)&ssrc };
        hipLaunchCooperativeKernel((const void*)csr_k, dim3(625), dim3(256),
                                   args, 0, stream);
    }
    // 2) fused cvt + transw
    prep_k<<<2500 + 1024, 256, 0, stream>>>(feat, featb, W1, w1t, W2, w2t);
    // 3) gather
    gather_k<<<(N_NODES + 1) / 2, 128, 0, stream>>>(feat, featb, eps, offs, ssrc, rst_b16);
    // 4+5) GEMMs (r11 verbatim)
    const int MT = (N_NODES + 63) / 64;  // 157 row-tiles (last one overlaps)
    gemm_k<0, D_IN><<<dim3(D_HID / 64, MT), 64, 0, stream>>>(
        rst_b16, w1t, b1, nullptr, (void*)h_b16, N_NODES, D_HID);
    gemm_k<1, D_HID><<<dim3(D_IN / 64, MT), 64, 0, stream>>>(
        h_b16, w2t, b2, feat, (void*)out, N_NODES, D_IN);
}

// Round 13
// 183.921 us; speedup vs baseline: 2.1768x; 2.1768x over previous
//
#include <hip/hip_runtime.h>

typedef unsigned short u16;
typedef unsigned int u32;
typedef __bf16 bf16x8 __attribute__((ext_vector_type(8)));
typedef float f32x4 __attribute__((ext_vector_type(4)));

#define N_NODES 10000
#define N_EDGES 160000
#define D_IN 512
#define D_HID 1024

#define AS1 __attribute__((address_space(1)))
#define AS3 __attribute__((address_space(3)))

__device__ __forceinline__ u16 f2bf(float f) {
    union { float f; u32 u; } v; v.f = f;
    return (u16)((v.u + 0x7fffu + ((v.u >> 16) & 1u)) >> 16);
}
__device__ __forceinline__ float b2f(u32 h) {
    union { u32 u; float f; } v; v.u = h << 16; return v.f;
}

// ---- fused independent prep: hist (625 blk) | cvt feat->bf16 (2500 blk) |
// transW (1024 blk). All three depend only on inputs (+ memset for hist);
// no inter-phase ordering needed -> ordinary kernel, NO grid.sync (r12's
// cooperative csr_k cost 231us -- grid.sync ~55-70us/each on 8 XCDs).
// Saves 2 graph-node boundaries vs r11's separate hist/cvt/transw. ----
__global__ __launch_bounds__(256) void prep_k(const int* __restrict__ dst,
                                              int* __restrict__ counts,
                                              const float* __restrict__ feat,
                                              u16* __restrict__ featb,
                                              const float* __restrict__ W1,
                                              u16* __restrict__ w1t,
                                              const float* __restrict__ W2,
                                              u16* __restrict__ w2t) {
    int b = blockIdx.x;
    int t = threadIdx.x;
    if (b < 625) {                        // hist
        int e = b * 256 + t;
        if (e < N_EDGES) atomicAdd(&counts[dst[e]], 1);
        return;
    }
    if (b < 625 + 2500) {                 // cvt feat -> bf16, 8/thread
        int i = ((b - 625) * 256 + t) * 8;
        float4 a = *(const float4*)(feat + i);
        float4 c = *(const float4*)(feat + i + 4);
        uint4 o;
        o.x = (u32)f2bf(a.x) | ((u32)f2bf(a.y) << 16);
        o.y = (u32)f2bf(a.z) | ((u32)f2bf(a.w) << 16);
        o.z = (u32)f2bf(c.x) | ((u32)f2bf(c.y) << 16);
        o.w = (u32)f2bf(c.z) | ((u32)f2bf(c.w) << 16);
        *(uint4*)(featb + i) = o;
        return;
    }
    // transpose+convert: WT[n][k] = bf16(W[k][n])
    __shared__ float tile[32][33];
    b -= 3125;
    const float* W; u16* WT; int K, N, nt;
    if (b < 512) { W = W1; WT = w1t; K = D_IN;  N = D_HID; nt = 32; }
    else         { b -= 512; W = W2; WT = w2t; K = D_HID; N = D_IN;  nt = 16; }
    int n0 = (b % nt) * 32, k0 = (b / nt) * 32;
    int tx = t & 31, ty = t >> 5;
#pragma unroll
    for (int i = 0; i < 32; i += 8)
        tile[ty + i][tx] = W[(size_t)(k0 + ty + i) * N + n0 + tx];
    __syncthreads();
#pragma unroll
    for (int i = 0; i < 32; i += 8)
        WT[(size_t)(n0 + ty + i) * K + k0 + tx] = f2bf(tile[tx][ty + i]);
}

// ---- single-block scan via wave shuffles: offs[10001], cursor[10000] ----
__global__ __launch_bounds__(1024) void scan_k(const int* __restrict__ counts,
                                               int* __restrict__ offs,
                                               int* __restrict__ cursor) {
    __shared__ int wpre[16];
    int t = threadIdx.x, l = t & 63, w = t >> 6;
    int base = t * 10;
    int c[10];
    int lsum = 0;
#pragma unroll
    for (int i = 0; i < 10; i++) {
        int idx = base + i;
        c[i] = (idx < N_NODES) ? counts[idx] : 0;
        lsum += c[i];
    }
    int sc = lsum;
#pragma unroll
    for (int d = 1; d < 64; d <<= 1) {
        int v = __shfl_up(sc, d);
        if (l >= d) sc += v;
    }
    __shared__ int wsum[16];
    if (l == 63) wsum[w] = sc;
    __syncthreads();
    if (w == 0 && l < 16) {
        int v = wsum[l];
        int p = v;
#pragma unroll
        for (int d = 1; d < 16; d <<= 1) {
            int u = __shfl_up(p, d);
            if (l >= d) p += u;
        }
        wpre[l] = p - v;
    }
    __syncthreads();
    int run = wpre[w] + sc - lsum;
#pragma unroll
    for (int i = 0; i < 10; i++) {
        int idx = base + i;
        if (idx < N_NODES) { offs[idx] = run; cursor[idx] = run; run += c[i]; }
    }
    if (t == 1023) offs[N_NODES] = wpre[15] + sc;
}

// ---- reorder edges into dst-sorted order ----
__global__ void reorder_k(const int* __restrict__ src, const int* __restrict__ dst,
                          int* __restrict__ cursor, int* __restrict__ ssrc) {
    int e = blockIdx.x * 256 + threadIdx.x;
    if (e >= N_EDGES) return;
    int d = dst[e];
    int pos = atomicAdd(&cursor[d], 1);
    ssrc[pos] = src[e];
}

// ---- gather-sum, all-bf16 inputs: (1+eps)*featb[n] + sum featb[src] ----
// one wave (64 lanes) per node, 8 bf16 per lane; 8 edges in flight per iter.
// Self-row now read from featb (bf16, 1KB) instead of feat (fp32, 2KB):
// saves 10MB HBM reads; adds the same <=0.4% rounding the 16 neighbor terms
// already carry (output is bf16 anyway; absmax headroom ample).
__global__ __launch_bounds__(128) void gather_k(const u16* __restrict__ featb,
                                                const float* __restrict__ eps,
                                                const int* __restrict__ offs,
                                                const int* __restrict__ ssrc,
                                                u16* __restrict__ out) {
    int n = (blockIdx.x * 128 + threadIdx.x) >> 6;
    int l = threadIdx.x & 63;
    if (n >= N_NODES) return;
    int beg = offs[n], end = offs[n + 1];
    float s = 1.0f + eps[0];
    uint4 sv = *(const uint4*)(featb + (size_t)n * D_IN + l * 8);
    float acc[8] = { s * b2f(sv.x & 0xffffu), s * b2f(sv.x >> 16),
                     s * b2f(sv.y & 0xffffu), s * b2f(sv.y >> 16),
                     s * b2f(sv.z & 0xffffu), s * b2f(sv.z >> 16),
                     s * b2f(sv.w & 0xffffu), s * b2f(sv.w >> 16) };
#define ACC4(v) \
        acc[0] += b2f(v.x & 0xffffu); acc[1] += b2f(v.x >> 16); \
        acc[2] += b2f(v.y & 0xffffu); acc[3] += b2f(v.y >> 16); \
        acc[4] += b2f(v.z & 0xffffu); acc[5] += b2f(v.z >> 16); \
        acc[6] += b2f(v.w & 0xffffu); acc[7] += b2f(v.w >> 16);
    int e = beg;
    for (; e + 8 <= end; e += 8) {
        uint4 v[8];
#pragma unroll
        for (int q = 0; q < 8; q++) {
            int iq = ssrc[e + q];
            v[q] = *(const uint4*)(featb + (size_t)iq * D_IN + l * 8);
        }
#pragma unroll
        for (int q = 0; q < 8; q++) { ACC4(v[q]) }
    }
    for (; e + 4 <= end; e += 4) {
        int i0 = ssrc[e], i1 = ssrc[e + 1], i2 = ssrc[e + 2], i3 = ssrc[e + 3];
        uint4 v0 = *(const uint4*)(featb + (size_t)i0 * D_IN + l * 8);
        uint4 v1 = *(const uint4*)(featb + (size_t)i1 * D_IN + l * 8);
        uint4 v2 = *(const uint4*)(featb + (size_t)i2 * D_IN + l * 8);
        uint4 v3 = *(const uint4*)(featb + (size_t)i3 * D_IN + l * 8);
        ACC4(v0) ACC4(v1) ACC4(v2) ACC4(v3)
    }
    for (; e < end; e++) {
        int i0 = ssrc[e];
        uint4 v0 = *(const uint4*)(featb + (size_t)i0 * D_IN + l * 8);
        ACC4(v0)
    }
#undef ACC4
    uint4 o;
    o.x = (u32)f2bf(acc[0]) | ((u32)f2bf(acc[1]) << 16);
    o.y = (u32)f2bf(acc[2]) | ((u32)f2bf(acc[3]) << 16);
    o.z = (u32)f2bf(acc[4]) | ((u32)f2bf(acc[5]) << 16);
    o.w = (u32)f2bf(acc[6]) | ((u32)f2bf(acc[7]) << 16);
    *(uint4*)(out + (size_t)n * D_IN + l * 8) = o;
}

// ---- GEMM: C[M,N] = A[M,K] @ B[K,N]; A bf16 row-major, BT bf16 [N,K] ----
// r11 verbatim (best measured): 64x64 tile, one wave/block, BK=32, 3-buffer
// depth-2 pipeline with exact counted vmcnt (safe: single wave, no other
// VMEM in loop), pre-swizzled gload_lds staging, XCD-chunked remap.
// EPI=0: C = bf16(relu(acc + bias));  EPI=1: C = acc + bias + feat (fp32)
template <int EPI, int K>
__global__ __launch_bounds__(64) void gemm_k(const u16* __restrict__ A,
                                             const u16* __restrict__ BT,
                                             const float* __restrict__ bias,
                                             const float* __restrict__ feat,
                                             void* __restrict__ Cout,
                                             int M, int N) {
    __shared__ __bf16 sA[3][64 * 32];
    __shared__ __bf16 sB[3][64 * 32];

    const int NX = gridDim.x;
    const int nwg = NX * gridDim.y;
    const int flat = blockIdx.y * NX + blockIdx.x;
    const int qq = nwg >> 3, rr8 = nwg & 7;
    const int xcd = flat & 7, idx = flat >> 3;
    const int L = (xcd < rr8 ? xcd * (qq + 1) : rr8 * (qq + 1) + (xcd - rr8) * qq) + idx;
    int row0 = (L / NX) * 64;
    if (row0 > M - 64) row0 = M - 64;   // overlap last tile; dup rows benign
    const int col0 = (L % NX) * 64;

    const int l = threadIdx.x;
    const int lr = l & 15;
    const int lq = l >> 4;

    const int g8 = (((l & 3) ^ ((l >> 2) & 3)) * 8);
    const u16* bA = A  + (size_t)(row0 + (l >> 2)) * K + g8;
    const u16* bB = BT + (size_t)(col0 + (l >> 2)) * K + g8;
    const int fo = ((lq ^ (lr & 3)) * 8);

    f32x4 acc[4][4] = {};
    const int NT = K >> 5;   // k-tiles of 32

#define STAGE(buf, kt)                                                         \
    {                                                                          \
        const int ko_ = (kt) << 5;                                             \
        _Pragma("unroll")                                                      \
        for (int q_ = 0; q_ < 4; q_++) {                                       \
            __builtin_amdgcn_global_load_lds(                                  \
                (const AS1 void*)(bA + (size_t)q_ * 16 * K + ko_),             \
                (AS3 void*)(&sA[buf][q_ * 512]), 16, 0, 0);                    \
            __builtin_amdgcn_global_load_lds(                                  \
                (const AS1 void*)(bB + (size_t)q_ * 16 * K + ko_),             \
                (AS3 void*)(&sB[buf][q_ * 512]), 16, 0, 0);                    \
        }                                                                      \
    }

    STAGE(0, 0);
    STAGE(1, 1);

#pragma unroll
    for (int it = 0; it < NT; ++it) {
        const int cur = it % 3;
        if (it == NT - 1) {
            asm volatile("s_waitcnt vmcnt(0)" ::: "memory");
        } else {
            asm volatile("s_waitcnt vmcnt(8)" ::: "memory");
        }
        __builtin_amdgcn_sched_barrier(0);
        bf16x8 fa[4], fb[4];
#pragma unroll
        for (int i = 0; i < 4; i++)
            fa[i] = *(const bf16x8*)(&sA[cur][0] + (i * 16 + lr) * 32 + fo);
#pragma unroll
        for (int j = 0; j < 4; j++)
            fb[j] = *(const bf16x8*)(&sB[cur][0] + (j * 16 + lr) * 32 + fo);
        __builtin_amdgcn_sched_barrier(0);
        if (it + 2 < NT) STAGE((it + 2) % 3, it + 2);
        __builtin_amdgcn_sched_barrier(0);
#pragma unroll
        for (int i = 0; i < 4; i++)
#pragma unroll
            for (int j = 0; j < 4; j++)
                acc[i][j] = __builtin_amdgcn_mfma_f32_16x16x32_bf16(
                    fa[i], fb[j], acc[i][j], 0, 0, 0);
    }
#undef STAGE

#pragma unroll
    for (int i = 0; i < 4; i++) {
        int rowb = row0 + i * 16 + lq * 4;
#pragma unroll
        for (int j = 0; j < 4; j++) {
            int col = col0 + j * 16 + lr;
            float bv = bias[col];
#pragma unroll
            for (int r = 0; r < 4; r++) {
                int rr = rowb + r;
                float v = acc[i][j][r] + bv;
                if (EPI == 0) {
                    v = fmaxf(v, 0.0f);
                    ((u16*)Cout)[(size_t)rr * N + col] = f2bf(v);
                } else {
                    v += feat[(size_t)rr * N + col];
                    ((float*)Cout)[(size_t)rr * N + col] = v;
                }
            }
        }
    }
}

extern "C" void kernel_launch(void* const* d_in, const int* in_sizes, int n_in,
                              void* d_out, int out_size, void* d_ws, size_t ws_size,
                              hipStream_t stream) {
    const float* feat = (const float*)d_in[0];
    const float* W1   = (const float*)d_in[1];
    const float* b1   = (const float*)d_in[2];
    const float* W2   = (const float*)d_in[3];
    const float* b2   = (const float*)d_in[4];
    const float* eps  = (const float*)d_in[5];
    const int*   src  = (const int*)d_in[6];
    const int*   dst  = (const int*)d_in[7];
    float* out = (float*)d_out;

    char* ws = (char*)d_ws;
    u16* rst_b16 = (u16*)(ws);                        // 10,240,000 B
    u16* h_b16   = (u16*)(ws + 10240000);             // 20,480,000 B
    u16* featb   = (u16*)(ws + 30720000);             // 10,240,000 B
    u16* w1t     = (u16*)(ws + 40960000);             //  1,048,576 B
    u16* w2t     = (u16*)(ws + 42008576);             //  1,048,576 B
    int* counts  = (int*)(ws + 43057152);             //     40,000 B
    int* offs    = (int*)(ws + 43097152);             //     40,004 B
    int* cursor  = (int*)(ws + 43137160);             //     40,000 B
    int* ssrc    = (int*)(ws + 43177160);             //    640,000 B

    hipMemsetAsync(counts, 0, N_NODES * sizeof(int), stream);
    // fused independent prep: hist | cvt | transw (no inter-phase deps)
    prep_k<<<625 + 2500 + 1024, 256, 0, stream>>>(dst, counts, feat, featb,
                                                  W1, w1t, W2, w2t);
    scan_k<<<1, 1024, 0, stream>>>(counts, offs, cursor);
    reorder_k<<<(N_EDGES + 255) / 256, 256, 0, stream>>>(src, dst, cursor, ssrc);

    gather_k<<<(N_NODES + 1) / 2, 128, 0, stream>>>(featb, eps, offs, ssrc, rst_b16);

    const int MT = (N_NODES + 63) / 64;  // 157 row-tiles (last one overlaps)
    gemm_k<0, D_IN><<<dim3(D_HID / 64, MT), 64, 0, stream>>>(
        rst_b16, w1t, b1, nullptr, (void*)h_b16, N_NODES, D_HID);
    gemm_k<1, D_HID><<<dim3(D_IN / 64, MT), 64, 0, stream>>>(
        h_b16, w2t, b2, feat, (void*)out, N_NODES, D_IN);
}